// Round 6
// baseline (164.648 us; speedup 1.0000x reference)
//
#include <hip/hip_runtime.h>
#include <math.h>

typedef __attribute__((ext_vector_type(8))) short short8;
typedef __attribute__((ext_vector_type(4))) float floatx4;

#define NH 4
#define HD 32
#define DIM 128
#define SEQ 256
#define BATCH 128
#define BS (BATCH*SEQ)
#define RANK 8
#define SCALING 2.0f
#define INV_SQRT_HD 0.17677669529663687f
#define LOG2E 1.4426950408889634f

#if __has_builtin(__builtin_amdgcn_exp2f)
#define EXP2F __builtin_amdgcn_exp2f
#else
#define EXP2F exp2f
#endif

// workspace byte offsets
#define XB_OFF  (0ull)        // x bf16 fragment-linear (8 MB)
#define WE_OFF  (9ull<<20)    // 4 x 128x128 bf16 weights, fragment-linear
#define TAB_OFF (10ull<<20)   // 256x16 float2 (cos,sin)

static __device__ __forceinline__ unsigned short f2bf(float f) {
    unsigned u = __float_as_uint(f);
    return (unsigned short)((u + 0x7FFFu + ((u >> 16) & 1u)) >> 16);
}
static __device__ __forceinline__ unsigned packbf(float lo, float hi) {
    unsigned ua = __float_as_uint(lo), ub = __float_as_uint(hi);
    ua += 0x7FFFu + ((ua >> 16) & 1u);
    ub += 0x7FFFu + ((ub >> 16) & 1u);
    return __builtin_amdgcn_perm(ub, ua, 0x07060302);  // (hi16(ub)<<16)|hi16(ua)
}

// ---------------------------------------------------------------------------
// prep: fragment-linear weights (LoRA folded; q gets 1/sqrt(hd)*log2e),
// RoPE table, x -> bf16 fragment-linear.  grid = 32 + 16 + 2048.
// ---------------------------------------------------------------------------
__global__ __launch_bounds__(256) void prep_kernel(
    const float* __restrict__ x,
    const float* __restrict__ wq, const float* __restrict__ wk,
    const float* __restrict__ wv, const float* __restrict__ wo,
    const float* __restrict__ Aq, const float* __restrict__ Bq,
    const float* __restrict__ Ak, const float* __restrict__ Bk,
    const float* __restrict__ Av, const float* __restrict__ Bv,
    unsigned short* __restrict__ weffL, float* __restrict__ tab,
    unsigned short* __restrict__ xbL)
{
    const int bid = blockIdx.x, tid = threadIdx.x;
    if (bid < 32) {
        int t = bid * 256 + tid;            // 0..8191
        int m    = t >> 11;
        int kc   = (t >> 9) & 3;
        int s    = (t >> 6) & 7;
        int lane = t & 63;
        int m16 = lane & 15, quad = lane >> 4;
        int row = (m < 3) ? ((s >> 1) * 32 + 2 * m16 + (s & 1)) : (s * 16 + m16);
        int col0 = kc * 32 + quad * 8;
        const float* W = m == 0 ? wq : (m == 1 ? wk : (m == 2 ? wv : wo));
        const float* A  = m == 0 ? Aq : (m == 1 ? Ak : Av);
        const float* Bm = m == 0 ? Bq : (m == 1 ? Bk : Bv);
        union { uint4 u4; unsigned short us[8]; } frag;
#pragma unroll
        for (int j = 0; j < 8; j++) {
            float val = W[row * DIM + col0 + j];
            if (m < 3) {
                float sacc = 0.f;
#pragma unroll
                for (int r = 0; r < RANK; r++)
                    sacc += Bm[row * RANK + r] * A[r * DIM + col0 + j];
                val += SCALING * sacc;
            }
            if (m == 0) val *= INV_SQRT_HD * LOG2E;   // exp2-based softmax
            frag.us[j] = f2bf(val);
        }
        *(uint4*)(weffL + (size_t)t * 8) = frag.u4;
    } else if (bid < 48) {
        int gid = (bid - 32) * 256 + tid;   // 0..4095
        int spos = gid >> 4, i = gid & 15;
        float invf = exp2f(-0.83048202f * (float)i);  // 10000^(-i/16)
        float ang = (float)spos * invf;
        float c, s;
        sincosf(ang, &s, &c);
        tab[gid * 2]     = c;
        tab[gid * 2 + 1] = s;
    } else {
        int t = (bid - 48) * 256 + tid;     // 0..524287
        int g    = t >> 8;
        int kc   = (t >> 6) & 3;
        int lane = t & 63;
        int m16 = lane & 15, quad = lane >> 4;
        const float* xp = x + (size_t)(g * 16 + m16) * DIM + kc * 32 + quad * 8;
        float4 f0 = *(const float4*)xp;
        float4 f1 = *(const float4*)(xp + 4);
        uint4 o;
        o.x = packbf(f0.x, f0.y); o.y = packbf(f0.z, f0.w);
        o.z = packbf(f1.x, f1.y); o.w = packbf(f1.z, f1.w);
        *(uint4*)(xbL + (size_t)t * 8) = o;
    }
}

// ---------------------------------------------------------------------------
// MEGA kernel: one block = one batch.  512 threads = 8 waves.
//  P0: each wave computes Q (+RoPE) for its 32 queries -> A-frags in regs
//      (via wave-private LDS transpose in scratch overlay).
//  Chunk loop (4 x 64 keys): waves 0-3 produce K(+RoPE) into LDS,
//      waves 4-7 produce V (pair-remapped kappa layout) into LDS; barrier;
//      all causally-active waves run QK->exp2->P->PV (max-free softmax,
//      ones-MFMA row sums); barrier.
//  P3: normalize O, wave-private LDS transpose to A-frags, out-proj GEMM,
//      fp32 stores.  No intermediate global traffic.
// ---------------------------------------------------------------------------
#define KSTS 40      // shorts per ks key row (80 B, 16B-aligned)
#define VSTU 68      // u32 per vs row (272 B, 16B-aligned)
#define QOSU 68      // u32 per staged token row (272 B)
#define PBU  20      // u32 per P row (80 B)

#define LDS_KS   (4*64*KSTS*2)            // 20480
#define LDS_VS   (64*VSTU*4)              // 17408
#define LDS_PB   (8*16*PBU*4)             // 10240

__global__ __launch_bounds__(512, 2) void mega_kernel(
    const unsigned short* __restrict__ xbL,
    const unsigned short* __restrict__ weffL,
    const float* __restrict__ tab,
    float* __restrict__ out)
{
    __shared__ __align__(16) char lds[LDS_KS + LDS_VS + LDS_PB];   // 48128 B
    unsigned short* ks  = (unsigned short*)lds;
    unsigned*       ksu = (unsigned*)lds;
    unsigned*       vs  = (unsigned*)(lds + LDS_KS);
    unsigned*       pb  = (unsigned*)(lds + LDS_KS + LDS_VS);
    unsigned*       qo  = (unsigned*)lds;          // scratch overlay (34816 B)

    const int b = blockIdx.x;
    const int tid = threadIdx.x;
    const int w = __builtin_amdgcn_readfirstlane(tid >> 6);
    const int lane = tid & 63;
    const int m16 = lane & 15, quad = lane >> 4;

    const short ob = (short)0x3F80;                // bf16 1.0
    const short8 bones = {ob, ob, ob, ob, ob, ob, ob, ob};
    const floatx4 z4 = (floatx4){0.f, 0.f, 0.f, 0.f};

    unsigned* qrow_w = qo + (size_t)w * 16 * QOSU; // wave-private 16 rows

    // ---------------- P0: Q for this wave's 32 queries ----------------
    short8 aq[2][NH];
#pragma unroll
    for (int qs = 0; qs < 2; qs++) {
        const int g = b * 16 + w * 2 + qs;
        short8 xf[4];
#pragma unroll
        for (int kc = 0; kc < 4; kc++)
            xf[kc] = *(const short8*)(xbL + ((size_t)(g * 4 + kc) * 64 + lane) * 8);
        floatx4 ae[NH], ao[NH];
#pragma unroll
        for (int h = 0; h < NH; h++) { ae[h] = z4; ao[h] = z4; }
#pragma unroll
        for (int kc = 0; kc < 4; kc++)
#pragma unroll
            for (int h = 0; h < NH; h++) {
                const unsigned short* bp = weffL + ((size_t)(kc * 8 + h * 2) * 64 + lane) * 8;
                short8 be = *(const short8*)bp;
                short8 bo = *(const short8*)(bp + 512);
                ae[h] = __builtin_amdgcn_mfma_f32_16x16x32_bf16(xf[kc], be, ae[h], 0, 0, 0);
                ao[h] = __builtin_amdgcn_mfma_f32_16x16x32_bf16(xf[kc], bo, ao[h], 0, 0, 0);
            }
        const int sbase = w * 32 + qs * 16 + quad * 4;
#pragma unroll
        for (int r = 0; r < 4; r++) {
            float2 cs = *(const float2*)(tab + ((size_t)(sbase + r) * 16 + m16) * 2);
#pragma unroll
            for (int h = 0; h < NH; h++) {
                float e = ae[h][r], o = ao[h][r];
                qrow_w[(quad * 4 + r) * QOSU + h * 16 + m16] =
                    packbf(e * cs.x - o * cs.y, e * cs.y + o * cs.x);
            }
        }
        // read back as QK A-frags (wave-private region; lgkmcnt by compiler)
#pragma unroll
        for (int h = 0; h < NH; h++)
            aq[qs][h] = *(const short8*)((const unsigned short*)qo
                        + ((size_t)(w * 16 + m16) * QOSU) * 2 + h * 32 + quad * 8);
    }
    __syncthreads();

    // ---------------- attention accumulators ----------------
    floatx4 oe[2][NH], oo[2][NH], ol[2][NH];
#pragma unroll
    for (int qs = 0; qs < 2; qs++)
#pragma unroll
        for (int h = 0; h < NH; h++) { oe[qs][h] = z4; oo[qs][h] = z4; ol[qs][h] = z4; }

    const int role_v = w >> 2;       // 0: produce K, 1: produce V
    const int sub = w & 3;           // 16-token slice within 64-key chunk

    for (int c = 0; c < 4; c++) {
        // -------- produce K/V for keys 64c..64c+63 --------
        {
            const int g = b * 16 + c * 4 + sub;
            short8 xf[4];
#pragma unroll
            for (int kc = 0; kc < 4; kc++)
                xf[kc] = *(const short8*)(xbL + ((size_t)(g * 4 + kc) * 64 + lane) * 8);
            const unsigned short* Wm = weffL + (size_t)(role_v ? 2 : 1) * DIM * DIM;
            floatx4 ae[NH], ao[NH];
#pragma unroll
            for (int h = 0; h < NH; h++) { ae[h] = z4; ao[h] = z4; }
#pragma unroll
            for (int kc = 0; kc < 4; kc++)
#pragma unroll
                for (int h = 0; h < NH; h++) {
                    const unsigned short* bp = Wm + ((size_t)(kc * 8 + h * 2) * 64 + lane) * 8;
                    short8 be = *(const short8*)bp;
                    short8 bo = *(const short8*)(bp + 512);
                    ae[h] = __builtin_amdgcn_mfma_f32_16x16x32_bf16(xf[kc], be, ae[h], 0, 0, 0);
                    ao[h] = __builtin_amdgcn_mfma_f32_16x16x32_bf16(xf[kc], bo, ao[h], 0, 0, 0);
                }
            if (!role_v) {           // K: RoPE + [h][key][dim] rows
                const int sbase = c * 64 + sub * 16 + quad * 4;
#pragma unroll
                for (int r = 0; r < 4; r++) {
                    float2 cs = *(const float2*)(tab + ((size_t)(sbase + r) * 16 + m16) * 2);
#pragma unroll
                    for (int h = 0; h < NH; h++) {
                        float e = ae[h][r], o = ao[h][r];
                        ksu[(size_t)(h * 64 + sub * 16 + quad * 4 + r) * (KSTS / 2) + m16] =
                            packbf(e * cs.x - o * cs.y, e * cs.y + o * cs.x);
                    }
                }
            } else {                 // V: kappa-permuted dim-pair rows
                const int t16 = sub & 1, s32 = sub >> 1;
#pragma unroll
                for (int r = 0; r < 4; r++) {
                    int kap = 8 * quad + 2 * r + t16;
                    int col = s32 * 32 + (kap ^ ((m16 & 3) << 3));
#pragma unroll
                    for (int h = 0; h < NH; h++)
                        vs[(size_t)(h * 16 + m16) * VSTU + col] = packbf(ae[h][r], ao[h][r]);
                }
            }
        }
        __syncthreads();
        // -------- consume (causally active waves) --------
        if (w >= 2 * c) {
            const int smax = (w - 2 * c >= 1) ? 2 : 1;
            unsigned* pw = pb + (size_t)w * 16 * PBU;
            for (int s32 = 0; s32 < smax; s32++) {
                const int k0 = c * 64 + s32 * 32;
#pragma unroll
                for (int h = 0; h < NH; h++) {
                    const unsigned short* kp = ks + (size_t)(h * 64 + s32 * 32) * KSTS;
                    short8 kb0 = *(const short8*)(kp + (size_t)m16 * KSTS + quad * 8);
                    short8 kb1 = *(const short8*)(kp + (size_t)(16 + m16) * KSTS + quad * 8);
                    const unsigned* vp = vs + (size_t)(h * 16 + m16) * VSTU + s32 * 32
                                       + ((quad ^ (m16 & 3)) * 8);
                    uint4 va = *(const uint4*)vp;
                    uint4 vb = *(const uint4*)(vp + 4);
                    union { short8 v; unsigned u[4]; } fe, fo;
                    fe.u[0] = __builtin_amdgcn_perm(va.y, va.x, 0x05040100u);
                    fe.u[1] = __builtin_amdgcn_perm(va.w, va.z, 0x05040100u);
                    fe.u[2] = __builtin_amdgcn_perm(vb.y, vb.x, 0x05040100u);
                    fe.u[3] = __builtin_amdgcn_perm(vb.w, vb.z, 0x05040100u);
                    fo.u[0] = __builtin_amdgcn_perm(va.y, va.x, 0x07060302u);
                    fo.u[1] = __builtin_amdgcn_perm(va.w, va.z, 0x07060302u);
                    fo.u[2] = __builtin_amdgcn_perm(vb.y, vb.x, 0x07060302u);
                    fo.u[3] = __builtin_amdgcn_perm(vb.w, vb.z, 0x07060302u);
#pragma unroll
                    for (int qs = 0; qs < 2; qs++) {
                        floatx4 s0 = __builtin_amdgcn_mfma_f32_16x16x32_bf16(aq[qs][h], kb0, z4, 0, 0, 0);
                        floatx4 s1 = __builtin_amdgcn_mfma_f32_16x16x32_bf16(aq[qs][h], kb1, z4, 0, 0, 0);
                        const int qg = w * 32 + qs * 16 + quad * 4;
#pragma unroll
                        for (int r = 0; r < 4; r++) {
                            float p0 = (k0 + m16      <= qg + r) ? EXP2F(s0[r]) : 0.f;
                            float p1 = (k0 + 16 + m16 <= qg + r) ? EXP2F(s1[r]) : 0.f;
                            pw[(quad * 4 + r) * PBU + m16] = packbf(p0, p1);
                        }
                        short8 ap = *(const short8*)((const unsigned short*)pw
                                    + m16 * (PBU * 2) + quad * 8);
                        oe[qs][h] = __builtin_amdgcn_mfma_f32_16x16x32_bf16(ap, fe.v, oe[qs][h], 0, 0, 0);
                        oo[qs][h] = __builtin_amdgcn_mfma_f32_16x16x32_bf16(ap, fo.v, oo[qs][h], 0, 0, 0);
                        ol[qs][h] = __builtin_amdgcn_mfma_f32_16x16x32_bf16(ap, bones, ol[qs][h], 0, 0, 0);
                    }
                }
            }
        }
        __syncthreads();
    }

    // ---------------- P3: normalize, transpose O, out-projection ----------------
    const unsigned short* Wo = weffL + (size_t)3 * DIM * DIM;
#pragma unroll
    for (int qs = 0; qs < 2; qs++) {
#pragma unroll
        for (int r = 0; r < 4; r++)
#pragma unroll
            for (int h = 0; h < NH; h++) {
                float inv = 1.f / ol[qs][h][r];
                qrow_w[(quad * 4 + r) * QOSU + h * 16 + m16] =
                    packbf(oe[qs][h][r] * inv, oo[qs][h][r] * inv);
            }
        short8 af[4];
#pragma unroll
        for (int kc = 0; kc < 4; kc++)
            af[kc] = *(const short8*)((const unsigned short*)qo
                     + ((size_t)(w * 16 + m16) * QOSU) * 2 + kc * 32 + quad * 8);
        floatx4 acc[8];
#pragma unroll
        for (int nt = 0; nt < 8; nt++) acc[nt] = z4;
#pragma unroll
        for (int kc = 0; kc < 4; kc++)
#pragma unroll
            for (int nt = 0; nt < 8; nt++) {
                short8 bf = *(const short8*)(Wo + ((size_t)(kc * 8 + nt) * 64 + lane) * 8);
                acc[nt] = __builtin_amdgcn_mfma_f32_16x16x32_bf16(af[kc], bf, acc[nt], 0, 0, 0);
            }
#pragma unroll
        for (int nt = 0; nt < 8; nt++)
#pragma unroll
            for (int r = 0; r < 4; r++)
                out[(size_t)(b * SEQ + w * 32 + qs * 16 + quad * 4 + r) * DIM
                    + nt * 16 + m16] = acc[nt][r];
    }
}

extern "C" void kernel_launch(void* const* d_in, const int* in_sizes, int n_in,
                              void* d_out, int out_size, void* d_ws, size_t ws_size,
                              hipStream_t stream)
{
    const float* x  = (const float*)d_in[0];
    const float* wq = (const float*)d_in[1];
    const float* wk = (const float*)d_in[2];
    const float* wv = (const float*)d_in[3];
    const float* wo = (const float*)d_in[4];
    const float* Aq = (const float*)d_in[5];
    const float* Bq = (const float*)d_in[6];
    const float* Ak = (const float*)d_in[7];
    const float* Bk = (const float*)d_in[8];
    const float* Av = (const float*)d_in[9];
    const float* Bv = (const float*)d_in[10];
    float* out = (float*)d_out;
    char* ws = (char*)d_ws;

    unsigned short* xbL   = (unsigned short*)(ws + XB_OFF);
    unsigned short* weffL = (unsigned short*)(ws + WE_OFF);
    float*          tab   = (float*)(ws + TAB_OFF);

    prep_kernel<<<48 + 2048, 256, 0, stream>>>(
        x, wq, wk, wv, wo, Aq, Bq, Ak, Bk, Av, Bv, weffL, tab, xbL);
    mega_kernel<<<BATCH, 512, 0, stream>>>(xbL, weffL, tab, out);
}